// Round 1
// baseline (580.077 us; speedup 1.0000x reference)
//
#include <hip/hip_runtime.h>

// GraphSSM: y_t = sum_s(C*h_t) + D*x_t, h_t = A*h_{t-1} + B*x_t  (diagonal SISO)
// Strength-reduced: g_t = A*g_{t-1} + x_t;  y_t = sum_s (C*B)*g_t + D*x_t
// One thread per (n, d) recurrence; state g[16] in registers.

constexpr int T_STEPS = 64;
constexpr int DIM = 128;
constexpr int DSTATE = 16;

__global__ __launch_bounds__(256) void graph_ssm_kernel(
    const float* __restrict__ seq,   // [T, N*DIM]
    const float* __restrict__ A,     // [DIM, DSTATE]
    const float* __restrict__ B,     // [DIM, DSTATE]
    const float* __restrict__ C,     // [DIM, DSTATE]
    const float* __restrict__ Dp,    // [DIM]
    float* __restrict__ out,         // [T, N*DIM]
    int S)                           // N*DIM
{
    const int tid = blockIdx.x * blockDim.x + threadIdx.x;
    if (tid >= S) return;
    const int d = tid & (DIM - 1);

    float a[DSTATE], cb[DSTATE], g[DSTATE];
#pragma unroll
    for (int s = 0; s < DSTATE; ++s) {
        a[s]  = A[d * DSTATE + s];
        cb[s] = C[d * DSTATE + s] * B[d * DSTATE + s];
        g[s]  = 0.0f;
    }
    const float dd = Dp[d];

    // Software-pipelined x prefetch (1 deep); loads are fully coalesced dwords.
    float x = seq[tid];
#pragma unroll 4
    for (int t = 0; t < T_STEPS; ++t) {
        float xn = 0.0f;
        if (t + 1 < T_STEPS) xn = seq[(size_t)(t + 1) * S + tid];

        // 4-way split accumulator to break the 16-FMA dependency chain.
        float y0 = dd * x, y1 = 0.0f, y2 = 0.0f, y3 = 0.0f;
#pragma unroll
        for (int s = 0; s < DSTATE; s += 4) {
            g[s + 0] = fmaf(a[s + 0], g[s + 0], x);
            y0 = fmaf(cb[s + 0], g[s + 0], y0);
            g[s + 1] = fmaf(a[s + 1], g[s + 1], x);
            y1 = fmaf(cb[s + 1], g[s + 1], y1);
            g[s + 2] = fmaf(a[s + 2], g[s + 2], x);
            y2 = fmaf(cb[s + 2], g[s + 2], y2);
            g[s + 3] = fmaf(a[s + 3], g[s + 3], x);
            y3 = fmaf(cb[s + 3], g[s + 3], y3);
        }
        out[(size_t)t * S + tid] = (y0 + y1) + (y2 + y3);
        x = xn;
    }
}

extern "C" void kernel_launch(void* const* d_in, const int* in_sizes, int n_in,
                              void* d_out, int out_size, void* d_ws, size_t ws_size,
                              hipStream_t stream) {
    const float* seq = (const float*)d_in[0];
    const float* A   = (const float*)d_in[1];
    const float* B   = (const float*)d_in[2];
    const float* C   = (const float*)d_in[3];
    const float* Dp  = (const float*)d_in[4];
    float* out = (float*)d_out;

    const int S = in_sizes[0] / T_STEPS;  // N*DIM
    const int block = 256;
    const int grid = (S + block - 1) / block;
    graph_ssm_kernel<<<grid, block, 0, stream>>>(seq, A, B, C, Dp, out, S);
}

// Round 2
// 560.818 us; speedup vs baseline: 1.0343x; 1.0343x over previous
//
#include <hip/hip_runtime.h>

// GraphSSM: h_t = A*h_{t-1} + B*x_t ; y_t = sum_s(C*h_t) + D*x_t   (diagonal SISO)
// Strength-reduced: g_t = A*g_{t-1} + x_t ; y_t = sum_s (C*B)*g_t + D*x_t
// One thread per (n,d) recurrence; state g[16] in registers.
// Round 2: 4-deep batched x prefetch (explicit double buffer) to fix the
// latency-bound stall seen in rocprof (VALUBusy 22%, hbm 30% of peak).

constexpr int T_STEPS = 64;
constexpr int DIM = 128;
constexpr int DSTATE = 16;
constexpr int CH = 4;  // prefetch depth; keeps VGPR < 64 (8 waves/SIMD)

__global__ __launch_bounds__(256) void graph_ssm_kernel(
    const float* __restrict__ seq,   // [T, N*DIM]
    const float* __restrict__ A,     // [DIM, DSTATE]
    const float* __restrict__ B,     // [DIM, DSTATE]
    const float* __restrict__ C,     // [DIM, DSTATE]
    const float* __restrict__ Dp,    // [DIM]
    float* __restrict__ out,         // [T, N*DIM]
    int S)                           // N*DIM
{
    const int tid = blockIdx.x * blockDim.x + threadIdx.x;
    if (tid >= S) return;
    const int d = tid & (DIM - 1);

    float a[DSTATE], cb[DSTATE], g[DSTATE];
#pragma unroll
    for (int s = 0; s < DSTATE; ++s) {
        a[s]  = A[d * DSTATE + s];
        cb[s] = C[d * DSTATE + s] * B[d * DSTATE + s];
        g[s]  = 0.0f;
    }
    const float dd = Dp[d];

    const float* sp = seq + tid;
    float* op = out + tid;

    // One timestep: update 16-wide state, dot with cb, store y (non-temporal
    // so the streamed output doesn't evict the input from L2/L3).
    auto step = [&](int t, float x) {
        float y0 = dd * x, y1 = 0.f, y2 = 0.f, y3 = 0.f;  // split acc: break dep chain
#pragma unroll
        for (int s = 0; s < DSTATE; s += 4) {
            g[s + 0] = fmaf(a[s + 0], g[s + 0], x);
            y0 = fmaf(cb[s + 0], g[s + 0], y0);
            g[s + 1] = fmaf(a[s + 1], g[s + 1], x);
            y1 = fmaf(cb[s + 1], g[s + 1], y1);
            g[s + 2] = fmaf(a[s + 2], g[s + 2], x);
            y2 = fmaf(cb[s + 2], g[s + 2], y2);
            g[s + 3] = fmaf(a[s + 3], g[s + 3], x);
            y3 = fmaf(cb[s + 3], g[s + 3], y3);
        }
        __builtin_nontemporal_store((y0 + y1) + (y2 + y3), op + (size_t)t * S);
    };

    float xb[CH], xn[CH];
#pragma unroll
    for (int j = 0; j < CH; ++j) xb[j] = sp[(size_t)j * S];

#pragma unroll 1   // keep the chunk loop rolled: small body, fits icache
    for (int tc = 0; tc < T_STEPS - CH; tc += CH) {
        // issue next chunk's 4 loads BEFORE computing current chunk:
        // 4 loads stay in flight under ~270 cy of VALU issue.
#pragma unroll
        for (int j = 0; j < CH; ++j) xn[j] = sp[(size_t)(tc + CH + j) * S];
#pragma unroll
        for (int j = 0; j < CH; ++j) step(tc + j, xb[j]);
#pragma unroll
        for (int j = 0; j < CH; ++j) xb[j] = xn[j];
    }
#pragma unroll
    for (int j = 0; j < CH; ++j) step(T_STEPS - CH + j, xb[j]);
}

extern "C" void kernel_launch(void* const* d_in, const int* in_sizes, int n_in,
                              void* d_out, int out_size, void* d_ws, size_t ws_size,
                              hipStream_t stream) {
    const float* seq = (const float*)d_in[0];
    const float* A   = (const float*)d_in[1];
    const float* B   = (const float*)d_in[2];
    const float* C   = (const float*)d_in[3];
    const float* Dp  = (const float*)d_in[4];
    float* out = (float*)d_out;

    const int S = in_sizes[0] / T_STEPS;  // N*DIM
    const int block = 256;
    const int grid = (S + block - 1) / block;
    graph_ssm_kernel<<<grid, block, 0, stream>>>(seq, A, B, C, Dp, out, S);
}

// Round 4
// 554.092 us; speedup vs baseline: 1.0469x; 1.0121x over previous
//
#include <hip/hip_runtime.h>

// GraphSSM: h_t = A*h_{t-1} + B*x_t ; y_t = sum_s(C*h_t) + D*x_t   (diagonal SISO)
// Strength-reduced: g_t = A*g_{t-1} + x_t ; y_t = sum_s (C*B)*g_t + D*x_t
// One thread per (n,d) recurrence; state g[16] in registers.
//
// Round 3 (resubmit after broker timeout): rocprof round-1 showed
// VGPR_Count=36 < 49 live params -> compiler was re-loading A/B/C (and
// re-computing C*B) every timestep = ~2048 extra latency-bound cache loads
// per thread. Pin params in VGPRs with an opaque asm barrier; deepen x
// prefetch to CH=8 to keep 8 loads in flight per wave.

constexpr int T_STEPS = 64;
constexpr int DIM = 128;
constexpr int DSTATE = 16;
constexpr int CH = 8;                 // prefetch depth (loads in flight per wave)
constexpr int S_FIX = 10000 * 128;    // N*DIM for the fixed problem size

template <int S>
__global__ __launch_bounds__(256) void graph_ssm_kernel(
    const float* __restrict__ seq,   // [T, S]
    const float* __restrict__ A,     // [DIM, DSTATE]
    const float* __restrict__ B,     // [DIM, DSTATE]
    const float* __restrict__ C,     // [DIM, DSTATE]
    const float* __restrict__ Dp,    // [DIM]
    float* __restrict__ out)         // [T, S]
{
    const int tid = blockIdx.x * blockDim.x + threadIdx.x;
    if (tid >= S) return;
    const int d = tid & (DIM - 1);

    float a[DSTATE], cb[DSTATE], g[DSTATE];
#pragma unroll
    for (int s = 0; s < DSTATE; ++s) {
        a[s]  = A[d * DSTATE + s];
        cb[s] = C[d * DSTATE + s] * B[d * DSTATE + s];
        g[s]  = 0.0f;
    }
    float dd = Dp[d];

    // Pin params in VGPRs: opaque to the compiler -> it cannot rematerialize
    // them by re-loading A/B/C inside the t-loop (round-1 failure mode).
#pragma unroll
    for (int s = 0; s < DSTATE; ++s) {
        asm volatile("" : "+v"(a[s]), "+v"(cb[s]));
    }
    asm volatile("" : "+v"(dd));

    const float* sp = seq + tid;
    float* op = out + tid;

    auto step = [&](int t, float x) {
        float y0 = dd * x, y1 = 0.f;   // 2-way split accumulator
#pragma unroll
        for (int s = 0; s < DSTATE; s += 2) {
            g[s + 0] = fmaf(a[s + 0], g[s + 0], x);
            y0 = fmaf(cb[s + 0], g[s + 0], y0);
            g[s + 1] = fmaf(a[s + 1], g[s + 1], x);
            y1 = fmaf(cb[s + 1], g[s + 1], y1);
        }
        // Non-temporal store: out is write-once, keep it out of L2/L3 so the
        // streamed input stays cache-resident.
        __builtin_nontemporal_store(y0 + y1, op + (size_t)t * S);
    };

    float xb[CH], xn[CH];
#pragma unroll
    for (int j = 0; j < CH; ++j) xb[j] = sp[(size_t)j * S];

#pragma unroll 1
    for (int tc = 0; tc < T_STEPS - CH; tc += CH) {
        // issue next chunk's CH loads before computing current chunk
#pragma unroll
        for (int j = 0; j < CH; ++j) xn[j] = sp[(size_t)(tc + CH + j) * S];
#pragma unroll
        for (int j = 0; j < CH; ++j) step(tc + j, xb[j]);
#pragma unroll
        for (int j = 0; j < CH; ++j) xb[j] = xn[j];
    }
#pragma unroll
    for (int j = 0; j < CH; ++j) step(T_STEPS - CH + j, xb[j]);
}

// Runtime-S fallback (same structure), in case sizes ever differ.
__global__ __launch_bounds__(256) void graph_ssm_kernel_dyn(
    const float* __restrict__ seq, const float* __restrict__ A,
    const float* __restrict__ B, const float* __restrict__ C,
    const float* __restrict__ Dp, float* __restrict__ out, int S)
{
    const int tid = blockIdx.x * blockDim.x + threadIdx.x;
    if (tid >= S) return;
    const int d = tid & (DIM - 1);
    float a[DSTATE], cb[DSTATE], g[DSTATE];
#pragma unroll
    for (int s = 0; s < DSTATE; ++s) {
        a[s]  = A[d * DSTATE + s];
        cb[s] = C[d * DSTATE + s] * B[d * DSTATE + s];
        g[s]  = 0.0f;
    }
    float dd = Dp[d];
#pragma unroll
    for (int s = 0; s < DSTATE; ++s) asm volatile("" : "+v"(a[s]), "+v"(cb[s]));
    asm volatile("" : "+v"(dd));
    const float* sp = seq + tid;
    float* op = out + tid;
    float x = sp[0];
    for (int t = 0; t < T_STEPS; ++t) {
        float xnext = (t + 1 < T_STEPS) ? sp[(size_t)(t + 1) * S] : 0.f;
        float y0 = dd * x, y1 = 0.f;
#pragma unroll
        for (int s = 0; s < DSTATE; s += 2) {
            g[s + 0] = fmaf(a[s + 0], g[s + 0], x);
            y0 = fmaf(cb[s + 0], g[s + 0], y0);
            g[s + 1] = fmaf(a[s + 1], g[s + 1], x);
            y1 = fmaf(cb[s + 1], g[s + 1], y1);
        }
        __builtin_nontemporal_store(y0 + y1, op + (size_t)t * S);
        x = xnext;
    }
}

extern "C" void kernel_launch(void* const* d_in, const int* in_sizes, int n_in,
                              void* d_out, int out_size, void* d_ws, size_t ws_size,
                              hipStream_t stream) {
    const float* seq = (const float*)d_in[0];
    const float* A   = (const float*)d_in[1];
    const float* B   = (const float*)d_in[2];
    const float* C   = (const float*)d_in[3];
    const float* Dp  = (const float*)d_in[4];
    float* out = (float*)d_out;

    const int S = in_sizes[0] / T_STEPS;  // N*DIM
    const int block = 256;
    const int grid = (S + block - 1) / block;
    if (S == S_FIX) {
        graph_ssm_kernel<S_FIX><<<grid, block, 0, stream>>>(seq, A, B, C, Dp, out);
    } else {
        graph_ssm_kernel_dyn<<<grid, block, 0, stream>>>(seq, A, B, C, Dp, out, S);
    }
}